// Round 3
// baseline (9.685 us; speedup 1.0000x reference)
//
#include <hip/hip_runtime.h>
#include <math.h>

#define FM_H 500
#define FM_W 440
#define ALPHA 0.25f
#define BLK 1024

__device__ __forceinline__ float focal_f(float p) {
    float q = 1.0f - p;
    return -logf(p) * ALPHA * q * q;
}

__device__ __forceinline__ float smooth_l1(float x) {
    float ax = fabsf(x);
    return ax < 1.0f ? 0.5f * x * x : ax - 0.5f;
}

__global__ __launch_bounds__(BLK) void ppl_kernel(
    const int*   __restrict__ reg_t,     // (B, NB, 2)  [xi, yi]
    const int*   __restrict__ bg_t,      // (B, NBG, 3) [_, x, y]
    const float* __restrict__ gt,        // (B, NB, 4)
    const float* __restrict__ loc,       // (B, 2, 3, H, W)
    const float* __restrict__ size_,     // (B, 2, 3, H, W)
    const float* __restrict__ clf,       // (B, 2, 3, H, W)
    const float* __restrict__ anchor_wh, // (2,)
    float* __restrict__ out,
    int B, int NB, int NBG)
{
    const int tid   = threadIdx.x;
    const int plane = FM_H * FM_W;
    const int per_b = 2 * 3 * plane;

    const int nbg_tot = B * NBG;
    const int nb_tot  = B * NB;
    const int max_tot = nbg_tot > nb_tot ? nbg_tot : nb_tot;

    float acc_main = 0.f;  // 2*(sl1 dx+dy+dw+dl) + focal(car), normalized by nb_tot
    float acc_bg   = 0.f;  // focal(bg), normalized by nbg_tot

    float aw0 = anchor_wh[0], aw1 = anchor_wh[1];
    float inv_da = rsqrtf(aw0 * aw0 + aw1 * aw1);

    // ---- fused loop: both dependent-load chains issue concurrently ----
    for (int i = tid; i < max_tot; i += BLK) {
        // background chain
        if (i < nbg_tot) {
            int b = i / NBG;
            const int* t = bg_t + i * 3;
            int x = t[1], y = t[2];
            float p = clf[b * per_b + y * FM_W + x];
            acc_bg += focal_f(p);
        }
        // car / localization chain
        if (i < nb_tot) {
            int b = i / NB;
            const int* t = reg_t + i * 2;
            int xi = t[0], yi = t[1];
            bool valid = (xi < FM_W) && (yi < FM_H);
            if (valid) {
                int xc = min(max(xi, 0), FM_W - 1);
                int yc = min(max(yi, 0), FM_H - 1);
                int base = b * per_b;
                int off  = yc * FM_W + xc;

                const float* g = gt + i * 4;
                float g0 = g[0], g1 = g[1], g2 = g[2], g3 = g[3];
                float w_gt = g3 - g1;
                float l_gt = g2 - g0;
                float x_gt = g0 + 0.5f * w_gt;
                float y_gt = g1 - 0.5f * l_gt;

                float x_pred = loc[base + off];
                float y_pred = loc[base + plane + off];
                float dx = (x_gt - x_pred) * inv_da;
                float dy = (y_gt - y_pred) * inv_da;
                float sw = fabsf(size_[base + off]);
                float sl = fabsf(size_[base + plane + off]);
                float dw = (w_gt != 0.f) ? logf(w_gt / sw) : 0.f;
                float dl = (l_gt != 0.f) ? logf(l_gt / sl) : 0.f;
                float p_car = clf[base + plane + off];

                acc_main += 2.0f * (smooth_l1(dx) + smooth_l1(dy) +
                                    smooth_l1(dw) + smooth_l1(dl))
                          + focal_f(p_car);
            }
        }
    }

    // ---- wave-level butterfly reduce (64 lanes, 2 accumulators) ----
    #pragma unroll
    for (int m = 32; m > 0; m >>= 1) {
        acc_main += __shfl_xor(acc_main, m, 64);
        acc_bg   += __shfl_xor(acc_bg,   m, 64);
    }

    // ---- cross-wave: 16 waves -> wave 0 ----
    __shared__ float red[16][2];
    const int wave = tid >> 6;
    const int lane = tid & 63;
    if (lane == 0) {
        red[wave][0] = acc_main;
        red[wave][1] = acc_bg;
    }
    __syncthreads();

    if (tid < 64) {
        float v0 = (lane < 16) ? red[lane][0] : 0.f;
        float v1 = (lane < 16) ? red[lane][1] : 0.f;
        #pragma unroll
        for (int m = 8; m > 0; m >>= 1) {
            v0 += __shfl_xor(v0, m, 64);
            v1 += __shfl_xor(v1, m, 64);
        }
        if (lane == 0)
            out[0] = v0 / (float)nb_tot + v1 / (float)nbg_tot;
    }
}

extern "C" void kernel_launch(void* const* d_in, const int* in_sizes, int n_in,
                              void* d_out, int out_size, void* d_ws, size_t ws_size,
                              hipStream_t stream) {
    const int*   reg_t     = (const int*)d_in[0];
    const int*   bg_t      = (const int*)d_in[1];
    const float* gt        = (const float*)d_in[2];
    const float* loc       = (const float*)d_in[3];
    const float* size_     = (const float*)d_in[4];
    const float* clf       = (const float*)d_in[5];
    const float* anchor_wh = (const float*)d_in[9];
    float* out = (float*)d_out;

    const int plane = FM_H * FM_W;
    int B   = in_sizes[3] / (2 * 3 * plane);
    int NB  = in_sizes[0] / (2 * B);
    int NBG = in_sizes[1] / (3 * B);

    ppl_kernel<<<1, BLK, 0, stream>>>(reg_t, bg_t, gt, loc, size_, clf,
                                      anchor_wh, out, B, NB, NBG);
}